// Round 6
// baseline (10322.797 us; speedup 1.0000x reference)
//
#include <hip/hip_runtime.h>
#include <cstdint>
#include <cstddef>

#define NENV 4096
#define SEQ  128
#define LATENT 64
#define EMB  256
#define HID  1024
#define SA   2

typedef _Float16 half8 __attribute__((ext_vector_type(8)));
typedef float f32x4 __attribute__((ext_vector_type(4)));

// assembler-encoded partial drain: wait until <= n vector-mem ops outstanding
#define WAITVM(n) asm volatile("s_waitcnt vmcnt(" #n ")" ::: "memory")
#define BARRIER() { __builtin_amdgcn_s_barrier(); asm volatile("" ::: "memory"); }

__device__ __forceinline__ float sigmoid_f(float x){ return 1.0f/(1.0f + __expf(-x)); }

__device__ __forceinline__ void dma16(const void* g, void* l){
  __builtin_amdgcn_global_load_lds(
      (const __attribute__((address_space(1))) void*)g,
      (__attribute__((address_space(3))) void*)l, 16, 0, 0);
}

// exactly ONE vmcnt op, guaranteed (no compiler splitting): 16B global->VGPR
__device__ __forceinline__ half8 gload16(const _Float16* p){
  half8 r;
  asm volatile("global_load_dwordx4 %0, %1, off"
               : "=v"(r) : "v"(p) : "memory");
  return r;
}

__device__ __forceinline__ f32x4 mfma16(half8 a, half8 b, f32x4 c){
  return __builtin_amdgcn_mfma_f32_16x16x32_f16(a, b, c, 0, 0, 0);
}

// bank swizzle (A tiles): element [row R][seg s] lives at slot R*4 + ((s + R + (R>>2)) & 3)
__device__ __forceinline__ int seg_for_slot(int R, int p){ return (p - R - (R >> 2)) & 3; }
__device__ __forceinline__ int phys_slot(int R, int q){ return R*4 + ((q + R + (R >> 2)) & 3); }

// ---------- pre-pass: transpose + fp32->fp16: in [K][C] -> out [C][K] ----------
__global__ void transpose_cvt_kernel(const float* __restrict__ in, _Float16* __restrict__ out,
                                     int K, int C){
  int n = K*C;
  for (int i = blockIdx.x*blockDim.x + threadIdx.x; i < n; i += gridDim.x*blockDim.x){
    int c = i / K;
    int k = i - c*K;
    out[i] = (_Float16)in[(size_t)k*C + c];
  }
}

__global__ void init_h_kernel(const float* __restrict__ rnn, _Float16* __restrict__ h16){
  int n = NENV*HID;
  for (int i = blockIdx.x*blockDim.x + threadIdx.x; i < n; i += gridDim.x*blockDim.x){
    h16[i] = (_Float16)rnn[i];
  }
}

// ---------- fused GRU: 128 rows x 64 h-cols x 3 gates, BK=32, depth-2 pipeline ----------
// A (activations, wave-shared) staged via global_load_lds into 3 x 512-slot buffers (24 KB).
// B (weights, wave-private 16-col fragments) loaded straight global->VGPR via inline asm:
// stage = exactly 2 A-DMAs + 3 B-loads = 5 vmcnt ops, so WAITVM(5) drains precisely one stage.
// sched_barrier(0) after each barrier pins MFMAs below the wait that validates their B regs.
template<int K, int NIT>
__device__ __forceinline__ void gru_phase(
    const _Float16* __restrict__ A, const _Float16* __restrict__ W,
    int r0, int c0, int tid, int wave, int m, int q,
    const int* pa, half8* sBuf,
    f32x4* accR, f32x4* accZ, f32x4* accN)
{
  const int RA0 = tid >> 2,        PA0 = tid & 3;
  const int RA1 = 64 + (tid >> 2), PA1 = tid & 3;
  const _Float16* gA0 = A + (size_t)(r0 + RA0)*K + seg_for_slot(RA0, PA0)*8;
  const _Float16* gA1 = A + (size_t)(r0 + RA1)*K + seg_for_slot(RA1, PA1)*8;
  const int bcol = c0 + wave*16 + m;
  const _Float16* gB0 = W + (size_t)(0*HID + bcol)*K + q*8;
  const _Float16* gB1 = W + (size_t)(1*HID + bcol)*K + q*8;
  const _Float16* gB2 = W + (size_t)(2*HID + bcol)*K + q*8;

  half8 br0, br1, br2, bz0, bz1, bz2, bn0, bn1, bn2;

#define GSTAGE(k, BR, BZ, BN) { \
    char* base_ = (char*)sBuf + (size_t)(((k) % 3))*512*16; \
    dma16(gA0, base_ + (size_t)(0   + wave*64)*16); \
    dma16(gA1, base_ + (size_t)(256 + wave*64)*16); \
    gA0 += 32; gA1 += 32; \
    BR = gload16(gB0 + (size_t)(k)*32); \
    BZ = gload16(gB1 + (size_t)(k)*32); \
    BN = gload16(gB2 + (size_t)(k)*32); }

#define GITER(it, BR, BZ, BN, BRn, BZn, BNn) \
  if ((it) < NIT) { \
    if ((it) < NIT - 1) { WAITVM(5); } else { WAITVM(0); } \
    BARRIER(); \
    __builtin_amdgcn_sched_barrier(0); \
    if ((it) + 2 < NIT) GSTAGE((it) + 2, BRn, BZn, BNn); \
    const half8* buf_ = sBuf + ((it) % 3)*512; \
    _Pragma("unroll") \
    for (int mt = 0; mt < 8; ++mt){ \
      half8 a_ = buf_[pa[mt]]; \
      accR[mt] = mfma16(a_, BR, accR[mt]); \
      accZ[mt] = mfma16(a_, BZ, accZ[mt]); \
      accN[mt] = mfma16(a_, BN, accN[mt]); \
    } \
  }

  GSTAGE(0, br0, bz0, bn0);
  GSTAGE(1, br1, bz1, bn1);
#pragma unroll
  for (int i3 = 0; i3 < NIT; i3 += 3){
    GITER(i3,     br0, bz0, bn0, br2, bz2, bn2);
    GITER(i3 + 1, br1, bz1, bn1, br0, bz0, bn0);
    GITER(i3 + 2, br2, bz2, bn2, br1, bz1, bn1);
  }
#undef GSTAGE
#undef GITER
  __syncthreads();   // all waves done with A buffers before next phase reuses them
}

__global__ __launch_bounds__(256, 2) void gru_kernel(
    const _Float16* __restrict__ x2h, const _Float16* __restrict__ hcur,
    const _Float16* __restrict__ wihT, const _Float16* __restrict__ whhT,
    const float* __restrict__ bih, const float* __restrict__ bhh,
    _Float16* __restrict__ hnxt, float* __restrict__ hout)
{
  __shared__ half8 sBuf[3*512];    // 24 KB (A tiles only)
  const int tid = threadIdx.x;
  const int lane = tid & 63, wave = tid >> 6;
  const int m = lane & 15, q = lane >> 4, n0 = wave*16;

  // XCD swizzle: XCD x owns colgroups {2x, 2x+1} -> W slice L2-resident
  const int id = blockIdx.x;
  const int colg = (id & 7)*2 + ((id >> 3) & 1);
  const int rowg = id >> 4;            // 0..31
  const int r0 = rowg*128, c0 = colg*64;

  int pa[8];
#pragma unroll
  for (int mt = 0; mt < 8; ++mt) pa[mt] = phys_slot(mt*16 + m, q);

  f32x4 accR[8], accZ[8], accNi[8], accNh[8];
#pragma unroll
  for (int i = 0; i < 8; ++i){
    accR[i] = (f32x4){0.f,0.f,0.f,0.f};
    accZ[i] = (f32x4){0.f,0.f,0.f,0.f};
    accNi[i] = (f32x4){0.f,0.f,0.f,0.f};
    accNh[i] = (f32x4){0.f,0.f,0.f,0.f};
  }

  gru_phase<EMB, EMB/32>(x2h,  wihT, r0, c0, tid, wave, m, q, pa, sBuf, accR, accZ, accNi);
  gru_phase<HID, HID/32>(hcur, whhT, r0, c0, tid, wave, m, q, pa, sBuf, accR, accZ, accNh);

  const int gc = c0 + n0 + m;
  const float b_r  = bih[gc]         + bhh[gc];
  const float b_z  = bih[gc + HID]   + bhh[gc + HID];
  const float b_in = bih[gc + 2*HID];
  const float b_hn = bhh[gc + 2*HID];
#pragma unroll
  for (int mt = 0; mt < 8; ++mt){
#pragma unroll
    for (int r = 0; r < 4; ++r){
      int grow = r0 + mt*16 + q*4 + r;
      float rr = sigmoid_f(accR[mt][r] + b_r);
      float u  = sigmoid_f(accZ[mt][r] + b_z);
      float nn = tanhf(accNi[mt][r] + b_in + rr*(accNh[mt][r] + b_hn));
      size_t idx = (size_t)grow*HID + gc;
      float hold = (float)hcur[idx];
      float hnew = (1.0f - u)*nn + u*hold;
      hnxt[idx] = (_Float16)hnew;
      if (hout) hout[idx] = hnew;
    }
  }
}

// ---------- o1 = relu(h @ w3 + b3) -> fp16, 64x64 tile, BK=32, pipelined ----------
// (verbatim verified baseline)
__global__ __launch_bounds__(256, 4) void out1_kernel(
    const _Float16* __restrict__ h16, const _Float16* __restrict__ w3T,
    const float* __restrict__ b3, _Float16* __restrict__ o1)
{
  __shared__ half8 sBuf[3*512];    // 24 KB
  const int tid = threadIdx.x;
  const int lane = tid & 63, wave = tid >> 6;
  const int m = lane & 15, q = lane >> 4, n0 = wave*16;

  const int id = blockIdx.x;
  const int colg = id & 7;     // XCD x owns col slice x (w3T slice 128 KB L2-resident)
  const int rowg = id >> 3;    // 0..63
  const int r0 = rowg*64, c0 = colg*64;

  int pa[4];
#pragma unroll
  for (int mt = 0; mt < 4; ++mt) pa[mt] = phys_slot(mt*16 + m, q);
  const int pb = phys_slot(n0 + m, q);

  f32x4 acc[4];
#pragma unroll
  for (int i = 0; i < 4; ++i) acc[i] = (f32x4){0.f,0.f,0.f,0.f};

  const int R = tid >> 2, P = tid & 3;
  const int sg = seg_for_slot(R, P);
  const _Float16* gA = h16 + (size_t)(r0 + R)*HID + sg*8;
  const _Float16* gB = w3T + (size_t)(c0 + R)*HID + sg*8;

  auto issue = [&](int bi){
    char* base = (char*)sBuf + (size_t)bi*512*16;
    dma16(gA, base + (size_t)(0   + wave*64)*16);
    dma16(gB, base + (size_t)(256 + wave*64)*16);
    gA += 32; gB += 32;
  };

  issue(0); issue(1);
#pragma unroll
  for (int it = 0; it < 32; ++it){
    if (it < 31) { WAITVM(2); } else { WAITVM(0); }
    BARRIER();
    if (it + 2 < 32) issue((it + 2) % 3);
    const half8* buf = sBuf + (it % 3)*512;
    half8 b = buf[256 + pb];
#pragma unroll
    for (int mt = 0; mt < 4; ++mt){
      half8 a = buf[pa[mt]];
      acc[mt] = mfma16(a, b, acc[mt]);
    }
  }

  const int gc = c0 + n0 + m;
  const float bb = b3[gc];
#pragma unroll
  for (int mt = 0; mt < 4; ++mt){
#pragma unroll
    for (int r = 0; r < 4; ++r){
      int grow = r0 + mt*16 + q*4 + r;
      o1[(size_t)grow*(HID/2) + gc] = (_Float16)fmaxf(acc[mt][r] + bb, 0.f);
    }
  }
}

// ---------- tail of step t fused with head of step t+1 ----------
// (verbatim verified baseline)
// mode 0: init (state=-2, x2 for t=0); mode 1: mid; mode 2: last (head only)
__global__ void tail_head_kernel(
    const _Float16* __restrict__ o1, const float* __restrict__ w4, const float* __restrict__ b4,
    const float* __restrict__ z,  const float* __restrict__ w1, const float* __restrict__ b1,
    const float* __restrict__ w2, const float* __restrict__ b2,
    _Float16* __restrict__ x2h, float* __restrict__ out, int t, int mode)
{
  __shared__ float sw2[32*256];   // 32 KB
  __shared__ float sw1[66*32];    // 8.4 KB
  __shared__ float sz[16][64];
  __shared__ float sx1[16][32];
  __shared__ float sst[16][2];
  const int tid = threadIdx.x;
  const int r0 = blockIdx.x*16;

  if (mode != 2){
    for (int i = tid; i < 66*32; i += 256) sw1[i] = w1[i];
    for (int i = tid; i < 32*256; i += 256) sw2[i] = w2[i];
    int zt = (mode == 0) ? 0 : (t + 1);
    for (int i = tid; i < 16*64; i += 256){
      int r = i >> 6, k = i & 63;
      sz[r][k] = z[(size_t)(r0 + r)*SEQ*LATENT + zt*LATENT + k];
    }
  }

  if (mode != 0){
    int r = tid >> 4, p = tid & 15;
    const _Float16* orow = o1 + (size_t)(r0 + r)*(HID/2);
    float a0 = 0.f, a1 = 0.f;
    for (int k = p*32; k < p*32 + 32; ++k){
      float v = (float)orow[k];
      a0 += v*w4[k*2];
      a1 += v*w4[k*2 + 1];
    }
#pragma unroll
    for (int off = 1; off < 16; off <<= 1){
      a0 += __shfl_xor(a0, off);
      a1 += __shfl_xor(a1, off);
    }
    if (p == 0){
      a0 = tanhf(a0 + b4[0]);
      a1 = tanhf(a1 + b4[1]);
      out[(size_t)(r0 + r)*SEQ*SA + t*SA + 0] = a0;
      out[(size_t)(r0 + r)*SEQ*SA + t*SA + 1] = a1;
      sst[r][0] = a0; sst[r][1] = a1;
    }
  } else {
    if (tid < 32) sst[tid >> 1][tid & 1] = -2.0f;
  }
  __syncthreads();

  if (mode != 2){
    for (int it = tid; it < 16*32; it += 256){
      int r = it >> 5, j = it & 31;
      float acc = b1[j];
      acc += sst[r][0]*sw1[0*32 + j] + sst[r][1]*sw1[1*32 + j];
#pragma unroll 8
      for (int k = 0; k < 64; ++k) acc += sz[r][k]*sw1[(k + 2)*32 + j];
      sx1[r][j] = fmaxf(acc, 0.f);
    }
    __syncthreads();
    int col = tid;
    for (int r = 0; r < 16; ++r){
      float acc = b2[col];
#pragma unroll
      for (int k = 0; k < 32; ++k) acc += sx1[r][k]*sw2[k*256 + col];
      x2h[(size_t)(r0 + r)*EMB + col] = (_Float16)fmaxf(acc, 0.f);
    }
  }
}

extern "C" void kernel_launch(void* const* d_in, const int* in_sizes, int n_in,
                              void* d_out, int out_size, void* d_ws, size_t ws_size,
                              hipStream_t stream) {
  const float* z   = (const float*)d_in[0];
  const float* rnn = (const float*)d_in[1];
  const float* w1  = (const float*)d_in[2];
  const float* b1  = (const float*)d_in[3];
  const float* w2  = (const float*)d_in[4];
  const float* b2  = (const float*)d_in[5];
  const float* wih = (const float*)d_in[6];
  const float* bih = (const float*)d_in[7];
  const float* whh = (const float*)d_in[8];
  const float* bhh = (const float*)d_in[9];
  const float* w3  = (const float*)d_in[10];
  const float* b3  = (const float*)d_in[11];
  const float* w4  = (const float*)d_in[12];
  const float* b4  = (const float*)d_in[13];
  float* out = (float*)d_out;

  char* ws = (char*)d_ws;
  _Float16* wihT = (_Float16*)ws;                 ws += (size_t)3*HID*EMB*2;
  _Float16* whhT = (_Float16*)ws;                 ws += (size_t)3*HID*HID*2;
  _Float16* w3T  = (_Float16*)ws;                 ws += (size_t)(HID/2)*HID*2;
  _Float16* h16a = (_Float16*)ws;                 ws += (size_t)NENV*HID*2;
  _Float16* h16b = (_Float16*)ws;                 ws += (size_t)NENV*HID*2;
  _Float16* x2h  = (_Float16*)ws;                 ws += (size_t)NENV*EMB*2;
  _Float16* o1   = (_Float16*)ws;                 ws += (size_t)NENV*(HID/2)*2;

  transpose_cvt_kernel<<<512, 256, 0, stream>>>(wih, wihT, EMB, 3*HID);
  transpose_cvt_kernel<<<1024, 256, 0, stream>>>(whh, whhT, HID, 3*HID);
  transpose_cvt_kernel<<<256, 256, 0, stream>>>(w3, w3T, HID, HID/2);
  init_h_kernel<<<1024, 256, 0, stream>>>(rnn, h16a);

  tail_head_kernel<<<NENV/16, 256, 0, stream>>>(o1, w4, b4, z, w1, b1, w2, b2, x2h, out, 0, 0);

  float* hfinal = out + (size_t)NENV*SEQ*SA;
  for (int t = 0; t < SEQ; ++t){
    _Float16* hc = (t & 1) ? h16b : h16a;
    _Float16* hn = (t & 1) ? h16a : h16b;
    gru_kernel<<<512, 256, 0, stream>>>(x2h, hc, wihT, whhT, bih, bhh, hn,
                                        (t == SEQ - 1) ? hfinal : nullptr);
    out1_kernel<<<512, 256, 0, stream>>>(hn, w3T, b3, o1);
    tail_head_kernel<<<NENV/16, 256, 0, stream>>>(o1, w4, b4, z, w1, b1, w2, b2, x2h, out,
                                                  t, (t < SEQ - 1) ? 1 : 2);
  }
}